// Round 2
// baseline (270.848 us; speedup 1.0000x reference)
//
#include <hip/hip_runtime.h>

#define NA 50000
#define NB 20000
#define NE0 600000
#define NE1 300000
#define NE2 300000
#define DD 128
#define SUB 32768     // keys per LDS histogram pass (16-bit packed counters, 64 KB)
#define PER 18750     // edges per group: NE0/32 = NE1/16 = NE2/16

// P packed-ushort cell layout (cell = Po[cfg] + g*K + k):
// cfg0 dout0 G=32,K=NA @0        ; cfg1 din0 G=32,K=NA @1600000
// cfg2 dout1 G=16,K=NA @3200000  ; cfg3 din1 G=16,K=NB @4000000
// cfg4 dout2 G=16,K=NB @4320000  ; cfg5 din2 G=16,K=NA @4640000
// CUM8 uchar layout: C0 @0 (32*NA) ; C1 @1600000 (16*NB) ; C2 @1920000 (16*NA)

typedef short bf16x8 __attribute__((ext_vector_type(8)));
typedef float f32x4 __attribute__((ext_vector_type(4)));
typedef unsigned int u32x4 __attribute__((ext_vector_type(4)));

__device__ __forceinline__ unsigned short f2bf(float f) {
    union { float f; unsigned int u; } v; v.f = f;
    unsigned int r = v.u + 0x7fffu + ((v.u >> 16) & 1u);   // RNE
    return (unsigned short)(r >> 16);
}
__device__ __forceinline__ float lo2f(unsigned int u) {
    union { float f; unsigned int u; } v; v.u = u << 16;
    return v.f;
}
__device__ __forceinline__ float hi2f(unsigned int u) {
    union { float f; unsigned int u; } v; v.u = u & 0xffff0000u;
    return v.f;
}

// ---- LDS histograms (z=0..5) + W->bf16 W^T transpose (z=6) ------------------
__global__ __launch_bounds__(1024) void hist_kernel(
    const int* __restrict__ s0, const int* __restrict__ d0,
    const int* __restrict__ s1, const int* __restrict__ d1,
    const int* __restrict__ s2, const int* __restrict__ d2,
    unsigned int* __restrict__ Pd,
    unsigned char* __restrict__ rank0, unsigned char* __restrict__ rank1,
    unsigned char* __restrict__ rank2,
    const float* __restrict__ W0, const float* __restrict__ W1,
    const float* __restrict__ W2, unsigned short* __restrict__ Wt)
{
    __shared__ unsigned int h32[SUB / 2];
    const int cfg = blockIdx.z;
    if (cfg == 6) {   // Wt[w][c*128+k] = bf16(W_w[k*128+c])
        int flat = blockIdx.y * 2 + blockIdx.x;
        if (flat >= 48) return;
        int i = flat * 1024 + threadIdx.x;
        int w = i >> 14, r = i & (DD * DD - 1);
        int c = r >> 7, k = r & (DD - 1);
        const float* W = (w == 0) ? W0 : ((w == 1) ? W1 : W2);
        Wt[i] = f2bf(__builtin_nontemporal_load(&W[k * DD + c]));
        return;
    }
    const int En[6] = {NE0, NE0, NE1, NE1, NE2, NE2};
    const int Kn[6] = {NA, NA, NA, NB, NB, NA};
    const int Gn[6] = {32, 32, 16, 16, 16, 16};
    const int Po[6] = {0, 1600000, 3200000, 4000000, 4320000, 4640000};
    int E = En[cfg], K = Kn[cfg], G = Gn[cfg];
    int sub = blockIdx.x, g = blockIdx.y;
    int nsub = (K + SUB - 1) / SUB;
    if (sub >= nsub || g >= G) return;
    const int* keys = cfg == 0 ? s0 : cfg == 1 ? d0 : cfg == 2 ? s1
                    : cfg == 3 ? d1 : cfg == 4 ? s2 : d2;
    unsigned char* rk = cfg == 1 ? rank0 : cfg == 3 ? rank1
                      : cfg == 5 ? rank2 : (unsigned char*)0;
    int lo = sub * SUB;
    int hi = min(K, lo + SUB);
    int cnt = hi - lo;
    for (int i = threadIdx.x; i < SUB / 2; i += 1024) h32[i] = 0;
    __syncthreads();
    int e1 = min(E, g * PER + PER);
    for (int e = g * PER + threadIdx.x; e < e1; e += 1024) {
        int k = __builtin_nontemporal_load(&keys[e]);
        if (k >= lo && k < hi) {
            int kk = k - lo;
            unsigned sh = (kk & 1) << 4;
            unsigned old = atomicAdd(&h32[kk >> 1], 1u << sh);
            if (rk) rk[e] = (unsigned char)((old >> sh) & 0xffu);
        }
    }
    __syncthreads();
    unsigned int* outp = Pd + ((Po[cfg] + g * K + lo) >> 1);
    for (int i = threadIdx.x; i < cnt / 2; i += 1024) outp[i] = h32[i];
}

// ---- fused: partial sums -> ideg/rdeg; din cfgs also emit CUM8 + spart ------
// 1 key per thread, fully coalesced. spart granularity: 256-key chunks.
__global__ __launch_bounds__(256) void reduce2(
    const unsigned short* __restrict__ P16, int* __restrict__ ideg,
    float* __restrict__ rdeg, int* __restrict__ spart,
    unsigned char* __restrict__ cum8)
{
    __shared__ int lds[256];
    const int y = blockIdx.y;
    const int Ro[6] = {0, NA, 2 * NA, 3 * NA, 3 * NA + NB, 3 * NA + 2 * NB};
    const int Kr[6] = {NA, NA, NA, NB, NB, NA};
    const int Gr[6] = {32, 32, 16, 16, 16, 16};
    const int Po[6] = {0, 1600000, 3200000, 4000000, 4320000, 4640000};
    const int Co[6] = {0, 0, 0, 1600000, 0, 1920000};
    int K = Kr[y], G = Gr[y];
    int b = blockIdx.x, t = threadIdx.x;
    int nchunk = (K + 255) >> 8;
    if (b >= nchunk) return;
    int key = b * 256 + t;
    bool valid = key < K;
    bool din = (y == 1) || (y == 3) || (y == 5);
    const unsigned short* p = P16 + Po[y] + key;
    unsigned char* cb = cum8 + Co[y] + key;
    int run = 0;
    for (int g = 0; g < G; ++g) {
        if (din && valid) cb[g * K] = (unsigned char)run;
        run += valid ? __builtin_nontemporal_load(&p[g * K]) : 0;
    }
    if (valid) {
        ideg[Ro[y] + key] = run;
        rdeg[Ro[y] + key] = rsqrtf(fmaxf((float)run, 1.f));
    }
    if (din) {
        int slot = (y - 1) >> 1;
        lds[t] = run; __syncthreads();
        for (int o = 128; o > 0; o >>= 1) {
            if (t < o) lds[t] += lds[t + o];
            __syncthreads();
        }
        if (t == 0) spart[slot * 256 + b] = lds[0];
    }
}

// ---- rowptr scan: spine over 256-key spart chunks + block-local scan --------
__global__ __launch_bounds__(256) void scan3(
    const int* __restrict__ ideg, const int* __restrict__ spart,
    int* __restrict__ rp)
{
    __shared__ int lds[256];
    const int y = blockIdx.y;
    const int off[3] = {NA, 3 * NA, 3 * NA + 2 * NB};
    const int nn[3]  = {NA, NB, NA};
    const int ro[3]  = {0, NA, NA + NB};
    int n = nn[y];
    int b = blockIdx.x, t = threadIdx.x;
    if (b * 1024 >= n) return;

    // base = sum of spart chunks [0, 4b)
    lds[t] = (t < 4 * b) ? spart[y * 256 + t] : 0;
    __syncthreads();
    for (int o = 128; o > 0; o >>= 1) {
        if (t < o) lds[t] += lds[t + o];
        __syncthreads();
    }
    int pv = lds[0];
    __syncthreads();

    const int* deg = ideg + off[y];
    int base = b * 1024 + t * 4;
    int v[4]; int tsum = 0;
    #pragma unroll
    for (int k = 0; k < 4; ++k) {
        v[k] = (base + k < n) ? deg[base + k] : 0;
        tsum += v[k];
    }
    lds[t] = tsum; __syncthreads();
    for (int o = 1; o < 256; o <<= 1) {
        int x = (t >= o) ? lds[t - o] : 0;
        __syncthreads();
        lds[t] += x;
        __syncthreads();
    }
    int run = lds[t] - tsum + pv;
    int* rowptr = rp + ro[y];
    #pragma unroll
    for (int k = 0; k < 4; ++k) {
        if (base + k < n) rowptr[base + k] = run;
        run += v[k];
    }
}

// ---- fused work: MFMA GEMMs FIRST (blocks 0..547), placement after ----------
// Streaming traffic (hA/hB reads, m writes, edge reads) is NONTEMPORAL so the
// hot scatter structures (rp 480KB, cum8 2.7MB, csr 4.8MB) stay L2-resident:
// R1 showed 60MB of csr partial-line eviction churn (WRITE_SIZE 94MB vs 35.5MB
// useful) caused by GEMM streams evicting half-filled csr lines.
// place: pos = rp[d] + CUM8[g*K+d] + rank8[e]   (no global atomics)
__global__ __launch_bounds__(512) void work_kernel(
    const int* __restrict__ s0, const int* __restrict__ d0,
    const int* __restrict__ s1, const int* __restrict__ d1,
    const int* __restrict__ s2, const int* __restrict__ d2,
    const unsigned char* __restrict__ cum8,
    const unsigned char* __restrict__ rank0, const unsigned char* __restrict__ rank1,
    const unsigned char* __restrict__ rank2,
    const int* __restrict__ rp,
    int* __restrict__ csr0, int* __restrict__ csr1, int* __restrict__ csr2,
    const float* __restrict__ hA, const float* __restrict__ hB,
    const unsigned short* __restrict__ Wt, const float* __restrict__ rdeg,
    unsigned short* __restrict__ mA0, unsigned short* __restrict__ mA1,
    unsigned short* __restrict__ mB2)
{
    int bx = blockIdx.x;
    int wid  = threadIdx.x >> 6;
    int lane = threadIdx.x & 63;
    int quad = lane >> 4;
    int l16  = lane & 15;
    if (bx < 391) {   // ---- dual-W GEMM over hA ----
        int base = bx * 128 + wid * 16;
        if (base >= NA) return;
        int arow = base + l16;
        if (arow >= NA) arow = NA - 1;
        bf16x8 a[4];
        #pragma unroll
        for (int kk = 0; kk < 4; ++kk) {
            const f32x4* p = (const f32x4*)(hA + (size_t)arow * DD + kk * 32 + quad * 8);
            f32x4 u = __builtin_nontemporal_load(p);
            f32x4 w = __builtin_nontemporal_load(p + 1);
            bf16x8 t;
            t[0] = (short)f2bf(u[0]); t[1] = (short)f2bf(u[1]);
            t[2] = (short)f2bf(u[2]); t[3] = (short)f2bf(u[3]);
            t[4] = (short)f2bf(w[0]); t[5] = (short)f2bf(w[1]);
            t[6] = (short)f2bf(w[2]); t[7] = (short)f2bf(w[3]);
            a[kk] = t;
        }
        float rs0[4], rs1[4]; int orow0 = base + quad * 4;
        #pragma unroll
        for (int r = 0; r < 4; ++r) {
            int orow = orow0 + r; int c = orow < NA ? orow : 0;
            rs0[r] = rdeg[c]; rs1[r] = rdeg[2 * NA + c];
        }
        #pragma unroll
        for (int ct = 0; ct < 8; ++ct) {
            f32x4 acc0 = {0.f, 0.f, 0.f, 0.f};
            f32x4 acc1 = {0.f, 0.f, 0.f, 0.f};
            const unsigned short* wp = Wt + (size_t)(ct * 16 + l16) * DD + quad * 8;
            #pragma unroll
            for (int kk = 0; kk < 4; ++kk) {
                bf16x8 b0 = *(const bf16x8*)(wp + kk * 32);
                bf16x8 b1 = *(const bf16x8*)(wp + 16384 + kk * 32);
                acc0 = __builtin_amdgcn_mfma_f32_16x16x32_bf16(a[kk], b0, acc0, 0, 0, 0);
                acc1 = __builtin_amdgcn_mfma_f32_16x16x32_bf16(a[kk], b1, acc1, 0, 0, 0);
            }
            #pragma unroll
            for (int r = 0; r < 4; ++r) {
                int orow = orow0 + r;
                if (orow < NA) {
                    __builtin_nontemporal_store(f2bf(acc0[r] * rs0[r]),
                        &mA0[(size_t)orow * DD + ct * 16 + l16]);
                    __builtin_nontemporal_store(f2bf(acc1[r] * rs1[r]),
                        &mA1[(size_t)orow * DD + ct * 16 + l16]);
                }
            }
        }
        return;
    }
    if (bx < 548) {   // ---- W2 GEMM over hB ----
        int base = (bx - 391) * 128 + wid * 16;
        if (base >= NB) return;
        int arow = base + l16;
        if (arow >= NB) arow = NB - 1;
        bf16x8 a[4];
        #pragma unroll
        for (int kk = 0; kk < 4; ++kk) {
            const f32x4* p = (const f32x4*)(hB + (size_t)arow * DD + kk * 32 + quad * 8);
            f32x4 u = __builtin_nontemporal_load(p);
            f32x4 w = __builtin_nontemporal_load(p + 1);
            bf16x8 t;
            t[0] = (short)f2bf(u[0]); t[1] = (short)f2bf(u[1]);
            t[2] = (short)f2bf(u[2]); t[3] = (short)f2bf(u[3]);
            t[4] = (short)f2bf(w[0]); t[5] = (short)f2bf(w[1]);
            t[6] = (short)f2bf(w[2]); t[7] = (short)f2bf(w[3]);
            a[kk] = t;
        }
        float rs[4]; int orow0 = base + quad * 4;
        #pragma unroll
        for (int r = 0; r < 4; ++r) {
            int orow = orow0 + r;
            rs[r] = rdeg[3 * NA + NB + (orow < NB ? orow : 0)];
        }
        #pragma unroll
        for (int ct = 0; ct < 8; ++ct) {
            f32x4 acc = {0.f, 0.f, 0.f, 0.f};
            const unsigned short* wp = Wt + 32768 + (size_t)(ct * 16 + l16) * DD + quad * 8;
            #pragma unroll
            for (int kk = 0; kk < 4; ++kk) {
                bf16x8 b = *(const bf16x8*)(wp + kk * 32);
                acc = __builtin_amdgcn_mfma_f32_16x16x32_bf16(a[kk], b, acc, 0, 0, 0);
            }
            #pragma unroll
            for (int r = 0; r < 4; ++r) {
                int orow = orow0 + r;
                if (orow < NB)
                    __builtin_nontemporal_store(f2bf(acc[r] * rs[r]),
                        &mB2[(size_t)orow * DD + ct * 16 + l16]);
            }
        }
        return;
    }
    // ---- placement: 1172 blocks x 1024 edges (2 per thread, independent) ----
    int pb = bx - 548;
    int z = (pb < 586) ? 0 : (pb < 879) ? 1 : 2;
    const int zb[3] = {0, 586, 879};
    const int En[3] = {NE0, NE1, NE2};
    const int Kn[3] = {NA, NB, NA};
    const int Co[3] = {0, 1600000, 1920000};
    const int ro[3] = {0, NA, NA + NB};
    int E = En[z], K = Kn[z];
    const int* src = z == 0 ? s0 : z == 1 ? s1 : s2;
    const int* dst = z == 0 ? d0 : z == 1 ? d1 : d2;
    const unsigned char* rk = z == 0 ? rank0 : z == 1 ? rank1 : rank2;
    int* csr = z == 0 ? csr0 : z == 1 ? csr1 : csr2;
    int e0 = (pb - zb[z]) * 1024 + threadIdx.x;
    int e1 = e0 + 512;
    bool v0 = e0 < E, v1 = e1 < E;
    int ce0 = v0 ? e0 : 0, ce1 = v1 ? e1 : 0;
    // issue both independent chains together (coalesced nt reads first)
    int d_0 = __builtin_nontemporal_load(&dst[ce0]);
    int d_1 = __builtin_nontemporal_load(&dst[ce1]);
    int r_0 = __builtin_nontemporal_load(&rk[ce0]);
    int r_1 = __builtin_nontemporal_load(&rk[ce1]);
    int s_0 = __builtin_nontemporal_load(&src[ce0]);
    int s_1 = __builtin_nontemporal_load(&src[ce1]);
    int g0 = ce0 / PER;
    int g1 = ce1 / PER;
    int p0 = rp[ro[z] + d_0] + (int)cum8[Co[z] + g0 * K + d_0] + r_0;
    int p1 = rp[ro[z] + d_1] + (int)cum8[Co[z] + g1 * K + d_1] + r_1;
    if (v0) csr[p0] = s_0;
    if (v1) csr[p1] = s_1;
}

// ---- gather: uint4 loads, 16 lanes/row -> 4 edges per wave instruction ------
__device__ __forceinline__ void acc8(float* o, u32x4 u) {
    o[0] += lo2f(u[0]); o[1] += hi2f(u[0]);
    o[2] += lo2f(u[1]); o[3] += hi2f(u[1]);
    o[4] += lo2f(u[2]); o[5] += hi2f(u[2]);
    o[6] += lo2f(u[3]); o[7] += hi2f(u[3]);
}
__device__ __forceinline__ void gather_rel4(
    const char* __restrict__ Mb, const int* __restrict__ csr,
    int st, int n, int lane, int q, unsigned laneoff, float* o)
{
    for (int ch = 0; ch < n; ch += 64) {
        int m = n - ch; if (m > 64) m = 64;
        // coalesced nt prefetch of edge sources (read-once stream)
        int idx = __builtin_nontemporal_load(&csr[st + ch + (lane < m ? lane : m - 1)]);
        int j = 0;
        for (; j + 8 <= m; j += 8) {        // 2 loads in flight, 8 edges/iter
            int sA = __shfl(idx, j + q);
            int sB = __shfl(idx, j + 4 + q);
            u32x4 uA = *(const u32x4*)(Mb + (((unsigned)sA << 8) + laneoff));
            u32x4 uB = *(const u32x4*)(Mb + (((unsigned)sB << 8) + laneoff));
            acc8(o, uA); acc8(o, uB);
        }
        if (j + 4 <= m) {
            int s = __shfl(idx, j + q);
            u32x4 u = *(const u32x4*)(Mb + (((unsigned)s << 8) + laneoff));
            acc8(o, u);
            j += 4;
        }
        if (j < m) {                        // masked tail group
            int jj = j + q;
            float w = jj < m ? 1.f : 0.f;
            int s = __shfl(idx, jj < m ? jj : m - 1);
            u32x4 u = *(const u32x4*)(Mb + (((unsigned)s << 8) + laneoff));
            o[0] = fmaf(w, lo2f(u[0]), o[0]); o[1] = fmaf(w, hi2f(u[0]), o[1]);
            o[2] = fmaf(w, lo2f(u[1]), o[2]); o[3] = fmaf(w, hi2f(u[1]), o[3]);
            o[4] = fmaf(w, lo2f(u[2]), o[4]); o[5] = fmaf(w, hi2f(u[2]), o[5]);
            o[6] = fmaf(w, lo2f(u[3]), o[6]); o[7] = fmaf(w, hi2f(u[3]), o[7]);
        }
    }
}

// ---- fused gather: blocks [0,12500) -> out_A rows; [12500,17500) -> out_B ---
__global__ __launch_bounds__(256) void gather_all(
    const unsigned short* __restrict__ mA0, const unsigned short* __restrict__ mA1,
    const unsigned short* __restrict__ mB2,
    const int* __restrict__ csr0, const int* __restrict__ csr1,
    const int* __restrict__ csr2,
    const int* __restrict__ rp, const int* __restrict__ ideg,
    const float* __restrict__ rdeg,
    const float* __restrict__ b0, const float* __restrict__ b1,
    const float* __restrict__ b2,
    float* __restrict__ out)
{
    int wid = threadIdx.x >> 6, lane = threadIdx.x & 63;
    int q = lane >> 4, l16 = lane & 15;
    unsigned laneoff = (unsigned)l16 * 16u;
    float v[8];
    #pragma unroll
    for (int i = 0; i < 8; ++i) v[i] = 0.f;
    float* op;
    const float *bia, *bib;

    if (blockIdx.x < 12500) {
        int d = blockIdx.x * 4 + wid;   // always < NA
        float c[8];
        #pragma unroll
        for (int i = 0; i < 8; ++i) c[i] = 0.f;
        gather_rel4((const char*)mA0, csr0, rp[d], ideg[NA + d], lane, q, laneoff, v);
        gather_rel4((const char*)mB2, csr2, rp[NA + NB + d], ideg[3 * NA + 2 * NB + d],
                    lane, q, laneoff, c);
        float r0 = rdeg[NA + d], r2 = rdeg[3 * NA + 2 * NB + d];
        #pragma unroll
        for (int i = 0; i < 8; ++i) v[i] = v[i] * r0 + c[i] * r2;
        op = out + (size_t)d * DD;
        bia = b0; bib = b2;
    } else {
        int d = (blockIdx.x - 12500) * 4 + wid;   // always < NB
        gather_rel4((const char*)mA1, csr1, rp[NA + d], ideg[3 * NA + d],
                    lane, q, laneoff, v);
        float r1 = rdeg[3 * NA + d];
        #pragma unroll
        for (int i = 0; i < 8; ++i) v[i] *= r1;
        op = out + (size_t)(NA + d) * DD;
        bia = b1; bib = 0;
    }

    #pragma unroll
    for (int i = 0; i < 8; ++i) {
        v[i] += __shfl_down(v[i], 32);
        v[i] += __shfl_down(v[i], 16);
    }
    if (lane < 16) {
        int col = l16 * 8;
        float4 ba0 = *(const float4*)(bia + col);
        float4 ba1 = *(const float4*)(bia + col + 4);
        if (bib) {
            float4 bb0 = *(const float4*)(bib + col);
            float4 bb1 = *(const float4*)(bib + col + 4);
            ba0.x += bb0.x; ba0.y += bb0.y; ba0.z += bb0.z; ba0.w += bb0.w;
            ba1.x += bb1.x; ba1.y += bb1.y; ba1.z += bb1.z; ba1.w += bb1.w;
        }
        f32x4 o0 = {v[0] + ba0.x, v[1] + ba0.y, v[2] + ba0.z, v[3] + ba0.w};
        f32x4 o1 = {v[4] + ba1.x, v[5] + ba1.y, v[6] + ba1.z, v[7] + ba1.w};
        __builtin_nontemporal_store(o0, (f32x4*)(op + col));
        __builtin_nontemporal_store(o1, (f32x4*)(op + col + 4));
    }
}

extern "C" void kernel_launch(void* const* d_in, const int* in_sizes, int n_in,
                              void* d_out, int out_size, void* d_ws, size_t ws_size,
                              hipStream_t stream) {
    const float* hA = (const float*)d_in[0];
    const float* hB = (const float*)d_in[1];
    const float* W0 = (const float*)d_in[2];
    const float* b0 = (const float*)d_in[3];
    const float* W1 = (const float*)d_in[4];
    const float* b1 = (const float*)d_in[5];
    const float* W2 = (const float*)d_in[6];
    const float* b2 = (const float*)d_in[7];
    const int* s0 = (const int*)d_in[8];
    const int* d0 = (const int*)d_in[9];
    const int* s1 = (const int*)d_in[10];
    const int* d1 = (const int*)d_in[11];
    const int* s2 = (const int*)d_in[12];
    const int* d2 = (const int*)d_in[13];
    float* out = (float*)d_out;
    char* ws = (char*)d_ws;

    // ws layout. P16 (10.88 MB packed) aliases mA0 (dead before work_kernel's gemm).
    unsigned short* mA0 = (unsigned short*)(ws + 0);          // 12.8 MB
    unsigned short* mA1 = (unsigned short*)(ws + 12800000);   // 12.8 MB
    unsigned short* mB2 = (unsigned short*)(ws + 25600000);   // 5.12 MB
    unsigned short* P16 = (unsigned short*)(ws + 0);          // 10.88 MB packed counts
    unsigned int*   Pd  = (unsigned int*)(ws + 0);            // dword view of P16
    unsigned short* Wt  = (unsigned short*)(ws + 30720000);   // 96 KB
    float* rdeg         = (float*)(ws + 30818304);            // 960 KB
    int*   ideg         = (int*)  (ws + 31778304);            // 960 KB
    int*   rp           = (int*)  (ws + 32738304);            // 480 KB
    int*   spart        = (int*)  (ws + 33218304);            // 3 KB
    unsigned char* cum8 = (unsigned char*)(ws + 33221376);    // 2.72 MB
    unsigned char* rank0= (unsigned char*)(ws + 35941376);    // 600 KB
    unsigned char* rank1= (unsigned char*)(ws + 36541376);    // 300 KB
    unsigned char* rank2= (unsigned char*)(ws + 36841376);    // 300 KB
    int*   csr0         = (int*)  (ws + 37141376);            // 2.4 MB
    int*   csr1         = (int*)  (ws + 39541376);            // 1.2 MB
    int*   csr2         = (int*)  (ws + 40741376);            // 1.2 MB

    hist_kernel<<<dim3(2, 32, 7), 1024, 0, stream>>>(s0, d0, s1, d1, s2, d2,
        Pd, rank0, rank1, rank2, W0, W1, W2, Wt);
    reduce2<<<dim3(196, 6), 256, 0, stream>>>(P16, ideg, rdeg, spart, cum8);
    scan3<<<dim3(49, 3), 256, 0, stream>>>(ideg, spart, rp);
    work_kernel<<<548 + 1172, 512, 0, stream>>>(s0, d0, s1, d1, s2, d2,
        cum8, rank0, rank1, rank2, rp, csr0, csr1, csr2,
        hA, hB, Wt, rdeg, mA0, mA1, mB2);
    gather_all<<<12500 + 5000, 256, 0, stream>>>(mA0, mA1, mB2,
        csr0, csr1, csr2, rp, ideg, rdeg, b0, b1, b2, out);
}

// Round 4
// 264.283 us; speedup vs baseline: 1.0248x; 1.0248x over previous
//
#include <hip/hip_runtime.h>

#define NA 50000
#define NB 20000
#define NE0 600000
#define NE1 300000
#define NE2 300000
#define DD 128
#define SUB 32768     // keys per LDS histogram pass (16-bit packed counters, 64 KB)
#define PER 18750     // edges per group: NE0/32 = NE1/16 = NE2/16

// P packed-ushort cell layout (cell = Po[cfg] + g*K + k):
// cfg0 dout0 G=32,K=NA @0        ; cfg1 din0 G=32,K=NA @1600000
// cfg2 dout1 G=16,K=NA @3200000  ; cfg3 din1 G=16,K=NB @4000000
// cfg4 dout2 G=16,K=NB @4320000  ; cfg5 din2 G=16,K=NA @4640000
// CUM8 uchar cells:  C0 @0 (32*NA) ; C1 @1600000 (16*NB) ; C2 @1920000 (16*NA)
// POS32 int cells (in d_out!), same indexing: pos32[c] = rp[d] + cum8[c].
// Lifetime: written by scan3, read by work_kernel placement, dead before
// gather_all overwrites d_out. 10.88 MB <= out_size 35.84 MB.

typedef short bf16x8 __attribute__((ext_vector_type(8)));
typedef float f32x4 __attribute__((ext_vector_type(4)));

__device__ __forceinline__ unsigned short f2bf(float f) {
    union { float f; unsigned int u; } v; v.f = f;
    unsigned int r = v.u + 0x7fffu + ((v.u >> 16) & 1u);   // RNE
    return (unsigned short)(r >> 16);
}
__device__ __forceinline__ float lo2f(unsigned int u) {
    union { float f; unsigned int u; } v; v.u = u << 16;
    return v.f;
}
__device__ __forceinline__ float hi2f(unsigned int u) {
    union { float f; unsigned int u; } v; v.u = u & 0xffff0000u;
    return v.f;
}

// ---- LDS histograms (z=0..5) + W->bf16 W^T transpose (z=6) ------------------
__global__ __launch_bounds__(1024) void hist_kernel(
    const int* __restrict__ s0, const int* __restrict__ d0,
    const int* __restrict__ s1, const int* __restrict__ d1,
    const int* __restrict__ s2, const int* __restrict__ d2,
    unsigned int* __restrict__ Pd,
    unsigned char* __restrict__ rank0, unsigned char* __restrict__ rank1,
    unsigned char* __restrict__ rank2,
    const float* __restrict__ W0, const float* __restrict__ W1,
    const float* __restrict__ W2, unsigned short* __restrict__ Wt)
{
    __shared__ unsigned int h32[SUB / 2];
    const int cfg = blockIdx.z;
    if (cfg == 6) {   // Wt[w][c*128+k] = bf16(W_w[k*128+c])
        int flat = blockIdx.y * 2 + blockIdx.x;
        if (flat >= 48) return;
        int i = flat * 1024 + threadIdx.x;
        int w = i >> 14, r = i & (DD * DD - 1);
        int c = r >> 7, k = r & (DD - 1);
        const float* W = (w == 0) ? W0 : ((w == 1) ? W1 : W2);
        Wt[i] = f2bf(W[k * DD + c]);
        return;
    }
    const int En[6] = {NE0, NE0, NE1, NE1, NE2, NE2};
    const int Kn[6] = {NA, NA, NA, NB, NB, NA};
    const int Gn[6] = {32, 32, 16, 16, 16, 16};
    const int Po[6] = {0, 1600000, 3200000, 4000000, 4320000, 4640000};
    int E = En[cfg], K = Kn[cfg], G = Gn[cfg];
    int sub = blockIdx.x, g = blockIdx.y;
    int nsub = (K + SUB - 1) / SUB;
    if (sub >= nsub || g >= G) return;
    const int* keys = cfg == 0 ? s0 : cfg == 1 ? d0 : cfg == 2 ? s1
                    : cfg == 3 ? d1 : cfg == 4 ? s2 : d2;
    unsigned char* rk = cfg == 1 ? rank0 : cfg == 3 ? rank1
                      : cfg == 5 ? rank2 : (unsigned char*)0;
    int lo = sub * SUB;
    int hi = min(K, lo + SUB);
    int cnt = hi - lo;
    for (int i = threadIdx.x; i < SUB / 2; i += 1024) h32[i] = 0;
    __syncthreads();
    int e1 = min(E, g * PER + PER);
    for (int e = g * PER + threadIdx.x; e < e1; e += 1024) {
        int k = keys[e];
        if (k >= lo && k < hi) {
            int kk = k - lo;
            unsigned sh = (kk & 1) << 4;
            unsigned old = atomicAdd(&h32[kk >> 1], 1u << sh);
            if (rk) rk[e] = (unsigned char)((old >> sh) & 0xffu);
        }
    }
    __syncthreads();
    unsigned int* outp = Pd + ((Po[cfg] + g * K + lo) >> 1);
    for (int i = threadIdx.x; i < cnt / 2; i += 1024) outp[i] = h32[i];
}

// ---- fused: partial sums -> ideg/rdeg; din cfgs also emit CUM8 + spart ------
// 1 key per thread, fully coalesced. spart granularity: 256-key chunks.
__global__ __launch_bounds__(256) void reduce2(
    const unsigned short* __restrict__ P16, int* __restrict__ ideg,
    float* __restrict__ rdeg, int* __restrict__ spart,
    unsigned char* __restrict__ cum8)
{
    __shared__ int lds[256];
    const int y = blockIdx.y;
    const int Ro[6] = {0, NA, 2 * NA, 3 * NA, 3 * NA + NB, 3 * NA + 2 * NB};
    const int Kr[6] = {NA, NA, NA, NB, NB, NA};
    const int Gr[6] = {32, 32, 16, 16, 16, 16};
    const int Po[6] = {0, 1600000, 3200000, 4000000, 4320000, 4640000};
    const int Co[6] = {0, 0, 0, 1600000, 0, 1920000};
    int K = Kr[y], G = Gr[y];
    int b = blockIdx.x, t = threadIdx.x;
    int nchunk = (K + 255) >> 8;
    if (b >= nchunk) return;
    int key = b * 256 + t;
    bool valid = key < K;
    bool din = (y == 1) || (y == 3) || (y == 5);
    const unsigned short* p = P16 + Po[y] + key;
    unsigned char* cb = cum8 + Co[y] + key;
    int run = 0;
    for (int g = 0; g < G; ++g) {
        if (din && valid) cb[g * K] = (unsigned char)run;
        run += valid ? p[g * K] : 0;
    }
    if (valid) {
        ideg[Ro[y] + key] = run;
        rdeg[Ro[y] + key] = rsqrtf(fmaxf((float)run, 1.f));
    }
    if (din) {
        int slot = (y - 1) >> 1;
        lds[t] = run; __syncthreads();
        for (int o = 128; o > 0; o >>= 1) {
            if (t < o) lds[t] += lds[t + o];
            __syncthreads();
        }
        if (t == 0) spart[slot * 256 + b] = lds[0];
    }
}

// ---- rowptr scan + fused POS32 build ----------------------------------------
// pos32[Co+g*K+d] = rp[d] + cum8[Co+g*K+d]  -- collapses placement's two random
// loads (rp, cum8) into one. Built here because this block already has rp[d]
// in registers; the extra loads/stores are fully coalesced over d.
__global__ __launch_bounds__(256) void scan3(
    const int* __restrict__ ideg, const int* __restrict__ spart,
    int* __restrict__ rp, const unsigned char* __restrict__ cum8,
    int* __restrict__ pos32)
{
    __shared__ int lds[256];
    const int y = blockIdx.y;
    const int off[3] = {NA, 3 * NA, 3 * NA + 2 * NB};
    const int nn[3]  = {NA, NB, NA};
    const int ro[3]  = {0, NA, NA + NB};
    const int Gy[3]  = {32, 16, 16};
    const int Coy[3] = {0, 1600000, 1920000};
    int n = nn[y];
    int b = blockIdx.x, t = threadIdx.x;
    if (b * 1024 >= n) return;

    // base = sum of spart chunks [0, 4b)
    lds[t] = (t < 4 * b) ? spart[y * 256 + t] : 0;
    __syncthreads();
    for (int o = 128; o > 0; o >>= 1) {
        if (t < o) lds[t] += lds[t + o];
        __syncthreads();
    }
    int pv = lds[0];
    __syncthreads();

    const int* deg = ideg + off[y];
    int base = b * 1024 + t * 4;
    int v[4]; int tsum = 0;
    #pragma unroll
    for (int k = 0; k < 4; ++k) {
        v[k] = (base + k < n) ? deg[base + k] : 0;
        tsum += v[k];
    }
    lds[t] = tsum; __syncthreads();
    for (int o = 1; o < 256; o <<= 1) {
        int x = (t >= o) ? lds[t - o] : 0;
        __syncthreads();
        lds[t] += x;
        __syncthreads();
    }
    int run = lds[t] - tsum + pv;
    int* rowptr = rp + ro[y];
    int rv[4];
    #pragma unroll
    for (int k = 0; k < 4; ++k) {
        rv[k] = run;
        if (base + k < n) rowptr[base + k] = run;
        run += v[k];
    }
    // fused pos32 build (coalesced over key for each g)
    int G = Gy[y];
    const int Co_ = Coy[y];
    for (int g = 0; g < G; ++g) {
        #pragma unroll
        for (int k = 0; k < 4; ++k) {
            int key = base + k;
            if (key < n) {
                int c = Co_ + g * n + key;
                pos32[c] = rv[k] + (int)cum8[c];
            }
        }
    }
}

// ---- fused work: MFMA GEMMs FIRST (blocks 0..547), placement after ----------
// GEMM-first keeps the streaming/MFMA blocks resident from t=0 (R1: +4.5us).
// placement: pos = pos32[g*K+d] + rank8[e] -- ONE random load + one u16 store
// per edge (was rp + cum8 + 4B store = 3 random L2 transactions).
__global__ __launch_bounds__(512) void work_kernel(
    const int* __restrict__ s0, const int* __restrict__ d0,
    const int* __restrict__ s1, const int* __restrict__ d1,
    const int* __restrict__ s2, const int* __restrict__ d2,
    const unsigned char* __restrict__ rank0, const unsigned char* __restrict__ rank1,
    const unsigned char* __restrict__ rank2,
    const int* __restrict__ pos32,
    unsigned short* __restrict__ csr0, unsigned short* __restrict__ csr1,
    unsigned short* __restrict__ csr2,
    const float* __restrict__ hA, const float* __restrict__ hB,
    const unsigned short* __restrict__ Wt, const float* __restrict__ rdeg,
    unsigned short* __restrict__ mA0, unsigned short* __restrict__ mA1,
    unsigned short* __restrict__ mB2)
{
    int bx = blockIdx.x;
    int wid  = threadIdx.x >> 6;
    int lane = threadIdx.x & 63;
    int quad = lane >> 4;
    int l16  = lane & 15;
    if (bx < 391) {   // ---- dual-W GEMM over hA ----
        int base = bx * 128 + wid * 16;
        if (base >= NA) return;
        int arow = base + l16;
        if (arow >= NA) arow = NA - 1;
        bf16x8 a[4];
        #pragma unroll
        for (int kk = 0; kk < 4; ++kk) {
            const float4* p = (const float4*)(hA + (size_t)arow * DD + kk * 32 + quad * 8);
            float4 u = p[0], w = p[1];
            bf16x8 t;
            t[0] = (short)f2bf(u.x); t[1] = (short)f2bf(u.y);
            t[2] = (short)f2bf(u.z); t[3] = (short)f2bf(u.w);
            t[4] = (short)f2bf(w.x); t[5] = (short)f2bf(w.y);
            t[6] = (short)f2bf(w.z); t[7] = (short)f2bf(w.w);
            a[kk] = t;
        }
        float rs0[4], rs1[4]; int orow0 = base + quad * 4;
        #pragma unroll
        for (int r = 0; r < 4; ++r) {
            int orow = orow0 + r; int c = orow < NA ? orow : 0;
            rs0[r] = rdeg[c]; rs1[r] = rdeg[2 * NA + c];
        }
        #pragma unroll
        for (int ct = 0; ct < 8; ++ct) {
            f32x4 acc0 = {0.f, 0.f, 0.f, 0.f};
            f32x4 acc1 = {0.f, 0.f, 0.f, 0.f};
            const unsigned short* wp = Wt + (size_t)(ct * 16 + l16) * DD + quad * 8;
            #pragma unroll
            for (int kk = 0; kk < 4; ++kk) {
                bf16x8 b0 = *(const bf16x8*)(wp + kk * 32);
                bf16x8 b1 = *(const bf16x8*)(wp + 16384 + kk * 32);
                acc0 = __builtin_amdgcn_mfma_f32_16x16x32_bf16(a[kk], b0, acc0, 0, 0, 0);
                acc1 = __builtin_amdgcn_mfma_f32_16x16x32_bf16(a[kk], b1, acc1, 0, 0, 0);
            }
            #pragma unroll
            for (int r = 0; r < 4; ++r) {
                int orow = orow0 + r;
                if (orow < NA) {
                    mA0[(size_t)orow * DD + ct * 16 + l16] = f2bf(acc0[r] * rs0[r]);
                    mA1[(size_t)orow * DD + ct * 16 + l16] = f2bf(acc1[r] * rs1[r]);
                }
            }
        }
        return;
    }
    if (bx < 548) {   // ---- W2 GEMM over hB ----
        int base = (bx - 391) * 128 + wid * 16;
        if (base >= NB) return;
        int arow = base + l16;
        if (arow >= NB) arow = NB - 1;
        bf16x8 a[4];
        #pragma unroll
        for (int kk = 0; kk < 4; ++kk) {
            const float4* p = (const float4*)(hB + (size_t)arow * DD + kk * 32 + quad * 8);
            float4 u = p[0], w = p[1];
            bf16x8 t;
            t[0] = (short)f2bf(u.x); t[1] = (short)f2bf(u.y);
            t[2] = (short)f2bf(u.z); t[3] = (short)f2bf(u.w);
            t[4] = (short)f2bf(w.x); t[5] = (short)f2bf(w.y);
            t[6] = (short)f2bf(w.z); t[7] = (short)f2bf(w.w);
            a[kk] = t;
        }
        float rs[4]; int orow0 = base + quad * 4;
        #pragma unroll
        for (int r = 0; r < 4; ++r) {
            int orow = orow0 + r;
            rs[r] = rdeg[3 * NA + NB + (orow < NB ? orow : 0)];
        }
        #pragma unroll
        for (int ct = 0; ct < 8; ++ct) {
            f32x4 acc = {0.f, 0.f, 0.f, 0.f};
            const unsigned short* wp = Wt + 32768 + (size_t)(ct * 16 + l16) * DD + quad * 8;
            #pragma unroll
            for (int kk = 0; kk < 4; ++kk) {
                bf16x8 b = *(const bf16x8*)(wp + kk * 32);
                acc = __builtin_amdgcn_mfma_f32_16x16x32_bf16(a[kk], b, acc, 0, 0, 0);
            }
            #pragma unroll
            for (int r = 0; r < 4; ++r) {
                int orow = orow0 + r;
                if (orow < NB)
                    mB2[(size_t)orow * DD + ct * 16 + l16] = f2bf(acc[r] * rs[r]);
            }
        }
        return;
    }
    // ---- placement: 587 blocks x 2048 edges (4 per thread, independent) ----
    int pb = bx - 548;
    int z = (pb < 293) ? 0 : (pb < 440) ? 1 : 2;
    const int zb[3] = {0, 293, 440};
    const int En[3] = {NE0, NE1, NE2};
    const int Kn[3] = {NA, NB, NA};
    const int Co[3] = {0, 1600000, 1920000};
    int E = En[z], K = Kn[z];
    const int* src = z == 0 ? s0 : z == 1 ? s1 : s2;
    const int* dst = z == 0 ? d0 : z == 1 ? d1 : d2;
    const unsigned char* rk = z == 0 ? rank0 : z == 1 ? rank1 : rank2;
    unsigned short* csr = z == 0 ? csr0 : z == 1 ? csr1 : csr2;
    int ebase = (pb - zb[z]) * 2048 + threadIdx.x;
    int ce[4]; bool vv[4];
    #pragma unroll
    for (int j = 0; j < 4; ++j) {
        int e = ebase + j * 512;
        vv[j] = e < E;
        ce[j] = vv[j] ? e : 0;
    }
    int dd_[4], rr[4], ss[4];
    #pragma unroll
    for (int j = 0; j < 4; ++j) dd_[j] = dst[ce[j]];   // coalesced
    #pragma unroll
    for (int j = 0; j < 4; ++j) rr[j] = rk[ce[j]];     // coalesced
    #pragma unroll
    for (int j = 0; j < 4; ++j) ss[j] = src[ce[j]];    // coalesced
    int pp[4];
    #pragma unroll
    for (int j = 0; j < 4; ++j) {                      // 4 independent random loads
        int g = ce[j] / PER;
        pp[j] = pos32[Co[z] + g * K + dd_[j]] + rr[j];
    }
    #pragma unroll
    for (int j = 0; j < 4; ++j)
        if (vv[j]) csr[pp[j]] = (unsigned short)ss[j];
}

// ---- gather: uint4 loads, 16 lanes/row -> 4 edges per wave instruction ------
__device__ __forceinline__ void acc8(float* o, uint4 u) {
    o[0] += lo2f(u.x); o[1] += hi2f(u.x);
    o[2] += lo2f(u.y); o[3] += hi2f(u.y);
    o[4] += lo2f(u.z); o[5] += hi2f(u.z);
    o[6] += lo2f(u.w); o[7] += hi2f(u.w);
}
__device__ __forceinline__ void gather_rel4(
    const char* __restrict__ Mb, const unsigned short* __restrict__ csr,
    int st, int n, int lane, int q, unsigned laneoff, float* o)
{
    for (int ch = 0; ch < n; ch += 64) {
        int m = n - ch; if (m > 64) m = 64;
        int idx = csr[st + ch + (lane < m ? lane : m - 1)];  // coalesced prefetch
        int j = 0;
        for (; j + 8 <= m; j += 8) {        // 2 loads in flight, 8 edges/iter
            int sA = __shfl(idx, j + q);
            int sB = __shfl(idx, j + 4 + q);
            uint4 uA = *(const uint4*)(Mb + (((unsigned)sA << 8) + laneoff));
            uint4 uB = *(const uint4*)(Mb + (((unsigned)sB << 8) + laneoff));
            acc8(o, uA); acc8(o, uB);
        }
        if (j + 4 <= m) {
            int s = __shfl(idx, j + q);
            uint4 u = *(const uint4*)(Mb + (((unsigned)s << 8) + laneoff));
            acc8(o, u);
            j += 4;
        }
        if (j < m) {                        // masked tail group
            int jj = j + q;
            float w = jj < m ? 1.f : 0.f;
            int s = __shfl(idx, jj < m ? jj : m - 1);
            uint4 u = *(const uint4*)(Mb + (((unsigned)s << 8) + laneoff));
            o[0] = fmaf(w, lo2f(u.x), o[0]); o[1] = fmaf(w, hi2f(u.x), o[1]);
            o[2] = fmaf(w, lo2f(u.y), o[2]); o[3] = fmaf(w, hi2f(u.y), o[3]);
            o[4] = fmaf(w, lo2f(u.z), o[4]); o[5] = fmaf(w, hi2f(u.z), o[5]);
            o[6] = fmaf(w, lo2f(u.w), o[6]); o[7] = fmaf(w, hi2f(u.w), o[7]);
        }
    }
}

// ---- fused gather: blocks [0,12500) -> out_A rows; [12500,17500) -> out_B ---
__global__ __launch_bounds__(256) void gather_all(
    const unsigned short* __restrict__ mA0, const unsigned short* __restrict__ mA1,
    const unsigned short* __restrict__ mB2,
    const unsigned short* __restrict__ csr0, const unsigned short* __restrict__ csr1,
    const unsigned short* __restrict__ csr2,
    const int* __restrict__ rp, const int* __restrict__ ideg,
    const float* __restrict__ rdeg,
    const float* __restrict__ b0, const float* __restrict__ b1,
    const float* __restrict__ b2,
    float* __restrict__ out)
{
    int wid = threadIdx.x >> 6, lane = threadIdx.x & 63;
    int q = lane >> 4, l16 = lane & 15;
    unsigned laneoff = (unsigned)l16 * 16u;
    float v[8];
    #pragma unroll
    for (int i = 0; i < 8; ++i) v[i] = 0.f;
    float* op;
    const float *bia, *bib;

    if (blockIdx.x < 12500) {
        int d = blockIdx.x * 4 + wid;   // always < NA
        float c[8];
        #pragma unroll
        for (int i = 0; i < 8; ++i) c[i] = 0.f;
        gather_rel4((const char*)mA0, csr0, rp[d], ideg[NA + d], lane, q, laneoff, v);
        gather_rel4((const char*)mB2, csr2, rp[NA + NB + d], ideg[3 * NA + 2 * NB + d],
                    lane, q, laneoff, c);
        float r0 = rdeg[NA + d], r2 = rdeg[3 * NA + 2 * NB + d];
        #pragma unroll
        for (int i = 0; i < 8; ++i) v[i] = v[i] * r0 + c[i] * r2;
        op = out + (size_t)d * DD;
        bia = b0; bib = b2;
    } else {
        int d = (blockIdx.x - 12500) * 4 + wid;   // always < NB
        gather_rel4((const char*)mA1, csr1, rp[NA + d], ideg[3 * NA + d],
                    lane, q, laneoff, v);
        float r1 = rdeg[3 * NA + d];
        #pragma unroll
        for (int i = 0; i < 8; ++i) v[i] *= r1;
        op = out + (size_t)(NA + d) * DD;
        bia = b1; bib = 0;
    }

    #pragma unroll
    for (int i = 0; i < 8; ++i) {
        v[i] += __shfl_down(v[i], 32);
        v[i] += __shfl_down(v[i], 16);
    }
    if (lane < 16) {
        int col = l16 * 8;
        float4 ba0 = *(const float4*)(bia + col);
        float4 ba1 = *(const float4*)(bia + col + 4);
        if (bib) {
            float4 bb0 = *(const float4*)(bib + col);
            float4 bb1 = *(const float4*)(bib + col + 4);
            ba0.x += bb0.x; ba0.y += bb0.y; ba0.z += bb0.z; ba0.w += bb0.w;
            ba1.x += bb1.x; ba1.y += bb1.y; ba1.z += bb1.z; ba1.w += bb1.w;
        }
        float4 o0 = {v[0] + ba0.x, v[1] + ba0.y, v[2] + ba0.z, v[3] + ba0.w};
        float4 o1 = {v[4] + ba1.x, v[5] + ba1.y, v[6] + ba1.z, v[7] + ba1.w};
        *(float4*)(op + col) = o0;
        *(float4*)(op + col + 4) = o1;
    }
}

extern "C" void kernel_launch(void* const* d_in, const int* in_sizes, int n_in,
                              void* d_out, int out_size, void* d_ws, size_t ws_size,
                              hipStream_t stream) {
    const float* hA = (const float*)d_in[0];
    const float* hB = (const float*)d_in[1];
    const float* W0 = (const float*)d_in[2];
    const float* b0 = (const float*)d_in[3];
    const float* W1 = (const float*)d_in[4];
    const float* b1 = (const float*)d_in[5];
    const float* W2 = (const float*)d_in[6];
    const float* b2 = (const float*)d_in[7];
    const int* s0 = (const int*)d_in[8];
    const int* d0 = (const int*)d_in[9];
    const int* s1 = (const int*)d_in[10];
    const int* d1 = (const int*)d_in[11];
    const int* s2 = (const int*)d_in[12];
    const int* d2 = (const int*)d_in[13];
    float* out = (float*)d_out;
    char* ws = (char*)d_ws;

    // ws layout: IDENTICAL offsets to the proven 41.9MB layout (R0-R2), csr
    // shrunk to u16 in place. P16 (10.88 MB packed) aliases mA0 (dead before
    // work_kernel's gemm). pos32 lives in d_out (see header comment): written
    // by scan3, consumed by work_kernel, dead before gather_all writes out.
    unsigned short* mA0 = (unsigned short*)(ws + 0);          // 12.8 MB
    unsigned short* mA1 = (unsigned short*)(ws + 12800000);   // 12.8 MB
    unsigned short* mB2 = (unsigned short*)(ws + 25600000);   // 5.12 MB
    unsigned short* P16 = (unsigned short*)(ws + 0);          // 10.88 MB packed counts
    unsigned int*   Pd  = (unsigned int*)(ws + 0);            // dword view of P16
    unsigned short* Wt  = (unsigned short*)(ws + 30720000);   // 96 KB
    float* rdeg         = (float*)(ws + 30818304);            // 960 KB slot
    int*   ideg         = (int*)  (ws + 31778304);            // 960 KB slot
    int*   rp           = (int*)  (ws + 32738304);            // 480 KB
    int*   spart        = (int*)  (ws + 33218304);            // 3 KB
    unsigned char* cum8 = (unsigned char*)(ws + 33221376);    // 2.72 MB
    unsigned char* rank0= (unsigned char*)(ws + 35941376);    // 600 KB
    unsigned char* rank1= (unsigned char*)(ws + 36541376);    // 300 KB
    unsigned char* rank2= (unsigned char*)(ws + 36841376);    // 300 KB
    unsigned short* csr0= (unsigned short*)(ws + 37141376);   // 1.2 MB (u16)
    unsigned short* csr1= (unsigned short*)(ws + 38341376);   // 0.6 MB (u16)
    unsigned short* csr2= (unsigned short*)(ws + 38941376);   // 0.6 MB (u16)
    int*            pos32 = (int*)d_out;                      // 10.88 MB, in out!

    hist_kernel<<<dim3(2, 32, 7), 1024, 0, stream>>>(s0, d0, s1, d1, s2, d2,
        Pd, rank0, rank1, rank2, W0, W1, W2, Wt);
    reduce2<<<dim3(196, 6), 256, 0, stream>>>(P16, ideg, rdeg, spart, cum8);
    scan3<<<dim3(49, 3), 256, 0, stream>>>(ideg, spart, rp, cum8, pos32);
    work_kernel<<<548 + 587, 512, 0, stream>>>(s0, d0, s1, d1, s2, d2,
        rank0, rank1, rank2, pos32, csr0, csr1, csr2,
        hA, hB, Wt, rdeg, mA0, mA1, mB2);
    gather_all<<<12500 + 5000, 256, 0, stream>>>(mA0, mA1, mB2,
        csr0, csr1, csr2, rp, ideg, rdeg, b0, b1, b2, out);
}

// Round 5
// 243.121 us; speedup vs baseline: 1.1140x; 1.0870x over previous
//
#include <hip/hip_runtime.h>

#define NA 50000
#define NB 20000
#define NE0 600000
#define NE1 300000
#define NE2 300000
#define DD 128
#define SUB 32768     // keys per LDS histogram pass (16-bit packed counters, 64 KB)
#define PER 18750     // edges per group: NE0/32 = NE1/16 = NE2/16
#define PSUB 8192     // dst-keys per placement block (32 KB LDS counters)

// P packed-ushort cell layout (cell = Po[cfg] + g*K + k):
// cfg0 dout0 G=32,K=NA @0        ; cfg1 din0 G=32,K=NA @1600000
// cfg2 dout1 G=16,K=NA @3200000  ; cfg3 din1 G=16,K=NB @4000000
// cfg4 dout2 G=16,K=NB @4320000  ; cfg5 din2 G=16,K=NA @4640000
// CUM8 uchar cells:  C0 @0 (32*NA) ; C1 @1600000 (16*NB) ; C2 @1920000 (16*NA)

typedef short bf16x8 __attribute__((ext_vector_type(8)));
typedef float f32x4 __attribute__((ext_vector_type(4)));

__device__ __forceinline__ unsigned short f2bf(float f) {
    union { float f; unsigned int u; } v; v.f = f;
    unsigned int r = v.u + 0x7fffu + ((v.u >> 16) & 1u);   // RNE
    return (unsigned short)(r >> 16);
}
__device__ __forceinline__ float lo2f(unsigned int u) {
    union { float f; unsigned int u; } v; v.u = u << 16;
    return v.f;
}
__device__ __forceinline__ float hi2f(unsigned int u) {
    union { float f; unsigned int u; } v; v.u = u & 0xffff0000u;
    return v.f;
}

// ---- LDS histograms (z=0..5) + W->bf16 W^T transpose (z=6) ------------------
// (rank byte writes removed: placement now recomputes ranks in LDS)
__global__ __launch_bounds__(1024) void hist_kernel(
    const int* __restrict__ s0, const int* __restrict__ d0,
    const int* __restrict__ s1, const int* __restrict__ d1,
    const int* __restrict__ s2, const int* __restrict__ d2,
    unsigned int* __restrict__ Pd,
    const float* __restrict__ W0, const float* __restrict__ W1,
    const float* __restrict__ W2, unsigned short* __restrict__ Wt)
{
    __shared__ unsigned int h32[SUB / 2];
    const int cfg = blockIdx.z;
    if (cfg == 6) {   // Wt[w][c*128+k] = bf16(W_w[k*128+c])
        int flat = blockIdx.y * 2 + blockIdx.x;
        if (flat >= 48) return;
        int i = flat * 1024 + threadIdx.x;
        int w = i >> 14, r = i & (DD * DD - 1);
        int c = r >> 7, k = r & (DD - 1);
        const float* W = (w == 0) ? W0 : ((w == 1) ? W1 : W2);
        Wt[i] = f2bf(W[k * DD + c]);
        return;
    }
    const int En[6] = {NE0, NE0, NE1, NE1, NE2, NE2};
    const int Kn[6] = {NA, NA, NA, NB, NB, NA};
    const int Gn[6] = {32, 32, 16, 16, 16, 16};
    const int Po[6] = {0, 1600000, 3200000, 4000000, 4320000, 4640000};
    int E = En[cfg], K = Kn[cfg], G = Gn[cfg];
    int sub = blockIdx.x, g = blockIdx.y;
    int nsub = (K + SUB - 1) / SUB;
    if (sub >= nsub || g >= G) return;
    const int* keys = cfg == 0 ? s0 : cfg == 1 ? d0 : cfg == 2 ? s1
                    : cfg == 3 ? d1 : cfg == 4 ? s2 : d2;
    int lo = sub * SUB;
    int hi = min(K, lo + SUB);
    int cnt = hi - lo;
    for (int i = threadIdx.x; i < SUB / 2; i += 1024) h32[i] = 0;
    __syncthreads();
    int e1 = min(E, g * PER + PER);
    for (int e = g * PER + threadIdx.x; e < e1; e += 1024) {
        int k = keys[e];
        if (k >= lo && k < hi) {
            int kk = k - lo;
            atomicAdd(&h32[kk >> 1], 1u << ((kk & 1) << 4));
        }
    }
    __syncthreads();
    unsigned int* outp = Pd + ((Po[cfg] + g * K + lo) >> 1);
    for (int i = threadIdx.x; i < cnt / 2; i += 1024) outp[i] = h32[i];
}

// ---- fused: partial sums -> ideg/rdeg; din cfgs also emit CUM8 + spart ------
// 1 key per thread, fully coalesced. spart granularity: 256-key chunks.
__global__ __launch_bounds__(256) void reduce2(
    const unsigned short* __restrict__ P16, int* __restrict__ ideg,
    float* __restrict__ rdeg, int* __restrict__ spart,
    unsigned char* __restrict__ cum8)
{
    __shared__ int lds[256];
    const int y = blockIdx.y;
    const int Ro[6] = {0, NA, 2 * NA, 3 * NA, 3 * NA + NB, 3 * NA + 2 * NB};
    const int Kr[6] = {NA, NA, NA, NB, NB, NA};
    const int Gr[6] = {32, 32, 16, 16, 16, 16};
    const int Po[6] = {0, 1600000, 3200000, 4000000, 4320000, 4640000};
    const int Co[6] = {0, 0, 0, 1600000, 0, 1920000};
    int K = Kr[y], G = Gr[y];
    int b = blockIdx.x, t = threadIdx.x;
    int nchunk = (K + 255) >> 8;
    if (b >= nchunk) return;
    int key = b * 256 + t;
    bool valid = key < K;
    bool din = (y == 1) || (y == 3) || (y == 5);
    const unsigned short* p = P16 + Po[y] + key;
    unsigned char* cb = cum8 + Co[y] + key;
    int run = 0;
    for (int g = 0; g < G; ++g) {
        if (din && valid) cb[g * K] = (unsigned char)run;
        run += valid ? p[g * K] : 0;
    }
    if (valid) {
        ideg[Ro[y] + key] = run;
        rdeg[Ro[y] + key] = rsqrtf(fmaxf((float)run, 1.f));
    }
    if (din) {
        int slot = (y - 1) >> 1;
        lds[t] = run; __syncthreads();
        for (int o = 128; o > 0; o >>= 1) {
            if (t < o) lds[t] += lds[t + o];
            __syncthreads();
        }
        if (t == 0) spart[slot * 256 + b] = lds[0];
    }
}

// ---- rowptr scan: spine over 256-key spart chunks + block-local scan --------
__global__ __launch_bounds__(256) void scan3(
    const int* __restrict__ ideg, const int* __restrict__ spart,
    int* __restrict__ rp)
{
    __shared__ int lds[256];
    const int y = blockIdx.y;
    const int off[3] = {NA, 3 * NA, 3 * NA + 2 * NB};
    const int nn[3]  = {NA, NB, NA};
    const int ro[3]  = {0, NA, NA + NB};
    int n = nn[y];
    int b = blockIdx.x, t = threadIdx.x;
    if (b * 1024 >= n) return;

    // base = sum of spart chunks [0, 4b)
    lds[t] = (t < 4 * b) ? spart[y * 256 + t] : 0;
    __syncthreads();
    for (int o = 128; o > 0; o >>= 1) {
        if (t < o) lds[t] += lds[t + o];
        __syncthreads();
    }
    int pv = lds[0];
    __syncthreads();

    const int* deg = ideg + off[y];
    int base = b * 1024 + t * 4;
    int v[4]; int tsum = 0;
    #pragma unroll
    for (int k = 0; k < 4; ++k) {
        v[k] = (base + k < n) ? deg[base + k] : 0;
        tsum += v[k];
    }
    lds[t] = tsum; __syncthreads();
    for (int o = 1; o < 256; o <<= 1) {
        int x = (t >= o) ? lds[t - o] : 0;
        __syncthreads();
        lds[t] += x;
        __syncthreads();
    }
    int run = lds[t] - tsum + pv;
    int* rowptr = rp + ro[y];
    #pragma unroll
    for (int k = 0; k < 4; ++k) {
        if (base + k < n) rowptr[base + k] = run;
        run += v[k];
    }
}

// ---- fused work: MFMA GEMMs FIRST (blocks 0..547), LDS-placement after ------
// GEMM-first keeps streaming/MFMA blocks resident from t=0 (R1: +4.5us).
// Placement: block = (z, group g, 8192-wide dst range). Counter bases
// rp[d]+cum8[g*K+d] are staged in LDS (coalesced); edges stream coalesced;
// rank is RECOMPUTED via LDS atomicAdd (row order is a multiset -> order-
// invariant). Zero random L2 loads per edge (R1 had 2, R4's big-footprint
// fusion thrashed L2: FETCH +28MB). csr stores land in a ~200KB contiguous
// window per block -> L2-local, no partial-line churn.
// 32KB static LDS keeps 4 blocks/CU (wave-limit) for the GEMM blocks too.
__global__ __launch_bounds__(512) void work_kernel(
    const int* __restrict__ s0, const int* __restrict__ d0,
    const int* __restrict__ s1, const int* __restrict__ d1,
    const int* __restrict__ s2, const int* __restrict__ d2,
    const unsigned char* __restrict__ cum8, const int* __restrict__ rp,
    unsigned short* __restrict__ csr0, unsigned short* __restrict__ csr1,
    unsigned short* __restrict__ csr2,
    const float* __restrict__ hA, const float* __restrict__ hB,
    const unsigned short* __restrict__ Wt, const float* __restrict__ rdeg,
    unsigned short* __restrict__ mA0, unsigned short* __restrict__ mA1,
    unsigned short* __restrict__ mB2)
{
    __shared__ int cnt_lds[PSUB];   // 32 KB
    int bx = blockIdx.x;
    int wid  = threadIdx.x >> 6;
    int lane = threadIdx.x & 63;
    int quad = lane >> 4;
    int l16  = lane & 15;
    if (bx < 391) {   // ---- dual-W GEMM over hA ----
        int base = bx * 128 + wid * 16;
        if (base >= NA) return;
        int arow = base + l16;
        if (arow >= NA) arow = NA - 1;
        bf16x8 a[4];
        #pragma unroll
        for (int kk = 0; kk < 4; ++kk) {
            const float4* p = (const float4*)(hA + (size_t)arow * DD + kk * 32 + quad * 8);
            float4 u = p[0], w = p[1];
            bf16x8 t;
            t[0] = (short)f2bf(u.x); t[1] = (short)f2bf(u.y);
            t[2] = (short)f2bf(u.z); t[3] = (short)f2bf(u.w);
            t[4] = (short)f2bf(w.x); t[5] = (short)f2bf(w.y);
            t[6] = (short)f2bf(w.z); t[7] = (short)f2bf(w.w);
            a[kk] = t;
        }
        float rs0[4], rs1[4]; int orow0 = base + quad * 4;
        #pragma unroll
        for (int r = 0; r < 4; ++r) {
            int orow = orow0 + r; int c = orow < NA ? orow : 0;
            rs0[r] = rdeg[c]; rs1[r] = rdeg[2 * NA + c];
        }
        #pragma unroll
        for (int ct = 0; ct < 8; ++ct) {
            f32x4 acc0 = {0.f, 0.f, 0.f, 0.f};
            f32x4 acc1 = {0.f, 0.f, 0.f, 0.f};
            const unsigned short* wp = Wt + (size_t)(ct * 16 + l16) * DD + quad * 8;
            #pragma unroll
            for (int kk = 0; kk < 4; ++kk) {
                bf16x8 b0 = *(const bf16x8*)(wp + kk * 32);
                bf16x8 b1 = *(const bf16x8*)(wp + 16384 + kk * 32);
                acc0 = __builtin_amdgcn_mfma_f32_16x16x32_bf16(a[kk], b0, acc0, 0, 0, 0);
                acc1 = __builtin_amdgcn_mfma_f32_16x16x32_bf16(a[kk], b1, acc1, 0, 0, 0);
            }
            #pragma unroll
            for (int r = 0; r < 4; ++r) {
                int orow = orow0 + r;
                if (orow < NA) {
                    mA0[(size_t)orow * DD + ct * 16 + l16] = f2bf(acc0[r] * rs0[r]);
                    mA1[(size_t)orow * DD + ct * 16 + l16] = f2bf(acc1[r] * rs1[r]);
                }
            }
        }
        return;
    }
    if (bx < 548) {   // ---- W2 GEMM over hB ----
        int base = (bx - 391) * 128 + wid * 16;
        if (base >= NB) return;
        int arow = base + l16;
        if (arow >= NB) arow = NB - 1;
        bf16x8 a[4];
        #pragma unroll
        for (int kk = 0; kk < 4; ++kk) {
            const float4* p = (const float4*)(hB + (size_t)arow * DD + kk * 32 + quad * 8);
            float4 u = p[0], w = p[1];
            bf16x8 t;
            t[0] = (short)f2bf(u.x); t[1] = (short)f2bf(u.y);
            t[2] = (short)f2bf(u.z); t[3] = (short)f2bf(u.w);
            t[4] = (short)f2bf(w.x); t[5] = (short)f2bf(w.y);
            t[6] = (short)f2bf(w.z); t[7] = (short)f2bf(w.w);
            a[kk] = t;
        }
        float rs[4]; int orow0 = base + quad * 4;
        #pragma unroll
        for (int r = 0; r < 4; ++r) {
            int orow = orow0 + r;
            rs[r] = rdeg[3 * NA + NB + (orow < NB ? orow : 0)];
        }
        #pragma unroll
        for (int ct = 0; ct < 8; ++ct) {
            f32x4 acc = {0.f, 0.f, 0.f, 0.f};
            const unsigned short* wp = Wt + 32768 + (size_t)(ct * 16 + l16) * DD + quad * 8;
            #pragma unroll
            for (int kk = 0; kk < 4; ++kk) {
                bf16x8 b = *(const bf16x8*)(wp + kk * 32);
                acc = __builtin_amdgcn_mfma_f32_16x16x32_bf16(a[kk], b, acc, 0, 0, 0);
            }
            #pragma unroll
            for (int r = 0; r < 4; ++r) {
                int orow = orow0 + r;
                if (orow < NB)
                    mB2[(size_t)orow * DD + ct * 16 + l16] = f2bf(acc[r] * rs[r]);
            }
        }
        return;
    }
    // ---- placement: 384 blocks = (z, g, sub) ----
    // z0: 32g x 7sub = 224 ; z1: 16g x 3sub = 48 ; z2: 16g x 7sub = 112
    int pb = bx - 548;
    int z, g, sub;
    if (pb < 224)      { z = 0; g = pb / 7;          sub = pb % 7; }
    else if (pb < 272) { z = 1; g = (pb - 224) / 3;  sub = (pb - 224) % 3; }
    else               { z = 2; g = (pb - 272) / 7;  sub = (pb - 272) % 7; }
    const int En[3] = {NE0, NE1, NE2};
    const int Kn[3] = {NA, NB, NA};
    const int Co[3] = {0, 1600000, 1920000};
    const int ro[3] = {0, NA, NA + NB};
    int E = En[z], K = Kn[z];
    const int* src = z == 0 ? s0 : z == 1 ? s1 : s2;
    const int* dst = z == 0 ? d0 : z == 1 ? d1 : d2;
    unsigned short* csr = z == 0 ? csr0 : z == 1 ? csr1 : csr2;
    int lo = sub * PSUB;
    int hi = min(K, lo + PSUB);
    int cnt = hi - lo;
    const int* rpz = rp + ro[z] + lo;
    const unsigned char* cz = cum8 + Co[z] + (size_t)g * K + lo;
    for (int i = threadIdx.x; i < cnt; i += 512)
        cnt_lds[i] = rpz[i] + (int)cz[i];
    __syncthreads();
    int e1 = min(E, g * PER + PER);
    for (int e = g * PER + threadIdx.x; e < e1; e += 512) {
        int d = dst[e];
        if (d >= lo && d < hi) {
            int pos = atomicAdd(&cnt_lds[d - lo], 1);
            csr[pos] = (unsigned short)src[e];
        }
    }
}

// ---- gather: uint4 loads, 16 lanes/row -> 4 edges per wave instruction ------
__device__ __forceinline__ void acc8(float* o, uint4 u) {
    o[0] += lo2f(u.x); o[1] += hi2f(u.x);
    o[2] += lo2f(u.y); o[3] += hi2f(u.y);
    o[4] += lo2f(u.z); o[5] += hi2f(u.z);
    o[6] += lo2f(u.w); o[7] += hi2f(u.w);
}
__device__ __forceinline__ void gather_rel4(
    const char* __restrict__ Mb, const unsigned short* __restrict__ csr,
    int st, int n, int lane, int q, unsigned laneoff, float* o)
{
    for (int ch = 0; ch < n; ch += 64) {
        int m = n - ch; if (m > 64) m = 64;
        int idx = csr[st + ch + (lane < m ? lane : m - 1)];  // coalesced prefetch
        int j = 0;
        for (; j + 8 <= m; j += 8) {        // 2 loads in flight, 8 edges/iter
            int sA = __shfl(idx, j + q);
            int sB = __shfl(idx, j + 4 + q);
            uint4 uA = *(const uint4*)(Mb + (((unsigned)sA << 8) + laneoff));
            uint4 uB = *(const uint4*)(Mb + (((unsigned)sB << 8) + laneoff));
            acc8(o, uA); acc8(o, uB);
        }
        if (j + 4 <= m) {
            int s = __shfl(idx, j + q);
            uint4 u = *(const uint4*)(Mb + (((unsigned)s << 8) + laneoff));
            acc8(o, u);
            j += 4;
        }
        if (j < m) {                        // masked tail group
            int jj = j + q;
            float w = jj < m ? 1.f : 0.f;
            int s = __shfl(idx, jj < m ? jj : m - 1);
            uint4 u = *(const uint4*)(Mb + (((unsigned)s << 8) + laneoff));
            o[0] = fmaf(w, lo2f(u.x), o[0]); o[1] = fmaf(w, hi2f(u.x), o[1]);
            o[2] = fmaf(w, lo2f(u.y), o[2]); o[3] = fmaf(w, hi2f(u.y), o[3]);
            o[4] = fmaf(w, lo2f(u.z), o[4]); o[5] = fmaf(w, hi2f(u.z), o[5]);
            o[6] = fmaf(w, lo2f(u.w), o[6]); o[7] = fmaf(w, hi2f(u.w), o[7]);
        }
    }
}

// ---- fused gather: blocks [0,12500) -> out_A rows; [12500,17500) -> out_B ---
__global__ __launch_bounds__(256) void gather_all(
    const unsigned short* __restrict__ mA0, const unsigned short* __restrict__ mA1,
    const unsigned short* __restrict__ mB2,
    const unsigned short* __restrict__ csr0, const unsigned short* __restrict__ csr1,
    const unsigned short* __restrict__ csr2,
    const int* __restrict__ rp, const int* __restrict__ ideg,
    const float* __restrict__ rdeg,
    const float* __restrict__ b0, const float* __restrict__ b1,
    const float* __restrict__ b2,
    float* __restrict__ out)
{
    int wid = threadIdx.x >> 6, lane = threadIdx.x & 63;
    int q = lane >> 4, l16 = lane & 15;
    unsigned laneoff = (unsigned)l16 * 16u;
    float v[8];
    #pragma unroll
    for (int i = 0; i < 8; ++i) v[i] = 0.f;
    float* op;
    const float *bia, *bib;

    if (blockIdx.x < 12500) {
        int d = blockIdx.x * 4 + wid;   // always < NA
        float c[8];
        #pragma unroll
        for (int i = 0; i < 8; ++i) c[i] = 0.f;
        gather_rel4((const char*)mA0, csr0, rp[d], ideg[NA + d], lane, q, laneoff, v);
        gather_rel4((const char*)mB2, csr2, rp[NA + NB + d], ideg[3 * NA + 2 * NB + d],
                    lane, q, laneoff, c);
        float r0 = rdeg[NA + d], r2 = rdeg[3 * NA + 2 * NB + d];
        #pragma unroll
        for (int i = 0; i < 8; ++i) v[i] = v[i] * r0 + c[i] * r2;
        op = out + (size_t)d * DD;
        bia = b0; bib = b2;
    } else {
        int d = (blockIdx.x - 12500) * 4 + wid;   // always < NB
        gather_rel4((const char*)mA1, csr1, rp[NA + d], ideg[3 * NA + d],
                    lane, q, laneoff, v);
        float r1 = rdeg[3 * NA + d];
        #pragma unroll
        for (int i = 0; i < 8; ++i) v[i] *= r1;
        op = out + (size_t)(NA + d) * DD;
        bia = b1; bib = 0;
    }

    #pragma unroll
    for (int i = 0; i < 8; ++i) {
        v[i] += __shfl_down(v[i], 32);
        v[i] += __shfl_down(v[i], 16);
    }
    if (lane < 16) {
        int col = l16 * 8;
        float4 ba0 = *(const float4*)(bia + col);
        float4 ba1 = *(const float4*)(bia + col + 4);
        if (bib) {
            float4 bb0 = *(const float4*)(bib + col);
            float4 bb1 = *(const float4*)(bib + col + 4);
            ba0.x += bb0.x; ba0.y += bb0.y; ba0.z += bb0.z; ba0.w += bb0.w;
            ba1.x += bb1.x; ba1.y += bb1.y; ba1.z += bb1.z; ba1.w += bb1.w;
        }
        float4 o0 = {v[0] + ba0.x, v[1] + ba0.y, v[2] + ba0.z, v[3] + ba0.w};
        float4 o1 = {v[4] + ba1.x, v[5] + ba1.y, v[6] + ba1.z, v[7] + ba1.w};
        *(float4*)(op + col) = o0;
        *(float4*)(op + col + 4) = o1;
    }
}

extern "C" void kernel_launch(void* const* d_in, const int* in_sizes, int n_in,
                              void* d_out, int out_size, void* d_ws, size_t ws_size,
                              hipStream_t stream) {
    const float* hA = (const float*)d_in[0];
    const float* hB = (const float*)d_in[1];
    const float* W0 = (const float*)d_in[2];
    const float* b0 = (const float*)d_in[3];
    const float* W1 = (const float*)d_in[4];
    const float* b1 = (const float*)d_in[5];
    const float* W2 = (const float*)d_in[6];
    const float* b2 = (const float*)d_in[7];
    const int* s0 = (const int*)d_in[8];
    const int* d0 = (const int*)d_in[9];
    const int* s1 = (const int*)d_in[10];
    const int* d1 = (const int*)d_in[11];
    const int* s2 = (const int*)d_in[12];
    const int* d2 = (const int*)d_in[13];
    float* out = (float*)d_out;
    char* ws = (char*)d_ws;

    // ws layout: R1-proven offsets; rank arrays deleted; csr u16 in their slot.
    // P16 (10.88 MB packed) aliases mA0 (dead before work_kernel's gemm).
    unsigned short* mA0 = (unsigned short*)(ws + 0);          // 12.8 MB
    unsigned short* mA1 = (unsigned short*)(ws + 12800000);   // 12.8 MB
    unsigned short* mB2 = (unsigned short*)(ws + 25600000);   // 5.12 MB
    unsigned short* P16 = (unsigned short*)(ws + 0);          // 10.88 MB packed counts
    unsigned int*   Pd  = (unsigned int*)(ws + 0);            // dword view of P16
    unsigned short* Wt  = (unsigned short*)(ws + 30720000);   // 96 KB
    float* rdeg         = (float*)(ws + 30818304);            // 960 KB slot
    int*   ideg         = (int*)  (ws + 31778304);            // 960 KB slot
    int*   rp           = (int*)  (ws + 32738304);            // 480 KB
    int*   spart        = (int*)  (ws + 33218304);            // 3 KB
    unsigned char* cum8 = (unsigned char*)(ws + 33221376);    // 2.72 MB
    unsigned short* csr0= (unsigned short*)(ws + 35941376);   // 1.2 MB (u16)
    unsigned short* csr1= (unsigned short*)(ws + 37141376);   // 0.6 MB (u16)
    unsigned short* csr2= (unsigned short*)(ws + 37741376);   // 0.6 MB (u16)

    hist_kernel<<<dim3(2, 32, 7), 1024, 0, stream>>>(s0, d0, s1, d1, s2, d2,
        Pd, W0, W1, W2, Wt);
    reduce2<<<dim3(196, 6), 256, 0, stream>>>(P16, ideg, rdeg, spart, cum8);
    scan3<<<dim3(49, 3), 256, 0, stream>>>(ideg, spart, rp);
    work_kernel<<<548 + 384, 512, 0, stream>>>(s0, d0, s1, d1, s2, d2,
        cum8, rp, csr0, csr1, csr2,
        hA, hB, Wt, rdeg, mA0, mA1, mB2);
    gather_all<<<12500 + 5000, 256, 0, stream>>>(mA0, mA1, mB2,
        csr0, csr1, csr2, rp, ideg, rdeg, b0, b1, b2, out);
}